// Round 11
// baseline (101.361 us; speedup 1.0000x reference)
//
#include <hip/hip_runtime.h>
#include <hip/hip_bf16.h>

constexpr int N_NODES = 50000;
constexpr int DIN     = 256;
constexpr int C_OUT   = 128;
constexpr int E_EDGES = 800000;
constexpr int ET      = E_EDGES + N_NODES;   // with self-loops
constexpr float NEG_SLOPE = 0.2f;

constexpr int NHI      = 196;                 // hi = dst >> 8
constexpr int CAP      = 6144;                // bucket capacity (mean 4337)
constexpr int PEPC     = 8192;                // edges per part block (256 thr x 32)
constexpr int NPB_PART = (ET + PEPC - 1) / PEPC;                   // 104
constexpr int WCONV_BLOCKS = (DIN * C_OUT) / 256;                  // 128
constexpr int GEMM_RPB    = 64;
constexpr int GEMM_BLOCKS = (N_NODES + GEMM_RPB - 1) / GEMM_RPB;   // 782
constexpr int AGG_NPB     = 32;
constexpr int AGG_BLOCKS  = (N_NODES + AGG_NPB - 1) / AGG_NPB;     // 1563

typedef __attribute__((ext_vector_type(8))) short short8v;
typedef __attribute__((ext_vector_type(4))) float f32x4;

static __device__ __forceinline__ ushort f2bf(float f) {
    __hip_bfloat16 b = __float2bfloat16(f);
    return *reinterpret_cast<ushort*>(&b);
}
static __device__ __forceinline__ short f2bfs(float f) {
    __hip_bfloat16 b = __float2bfloat16(f);
    return *reinterpret_cast<short*>(&b);
}

// ---------------------------------------------------------------------------
// D1 (fused): blocks [0,NPB_PART): bucket-partition edges -> packed ebuf
//   entry (lo<<16)|src. LDS histogram + one returning global atomic per
//   (block,bucket) + LDS-cursor scatter.
//   blocks [NPB_PART,+WCONV): Wt -> bf16 fragment-ordered.
// fragpos(ks,c,kgrp,col16,j) = ((ks*8+c)*64 + kgrp*16 + col16)*8 + j
// ---------------------------------------------------------------------------
__global__ __launch_bounds__(256) void part_wconv(const float* __restrict__ W,
                                                  const int* __restrict__ ei,
                                                  ushort* __restrict__ wt,
                                                  int* __restrict__ gcur,
                                                  int* __restrict__ ebuf) {
    const int t = threadIdx.x;
    if (blockIdx.x < NPB_PART) {             // ---- partition path ----
        __shared__ int hist[256], basel[256], curl[256];
        const int c = blockIdx.x;
        hist[t] = 0;
        __syncthreads();
        #pragma unroll 4
        for (int i = 0; i < 32; i++) {
            const int e = c * PEPC + i * 256 + t;
            if (e < ET) {
                const int d = (e < E_EDGES) ? ei[E_EDGES + e] : (e - E_EDGES);
                atomicAdd(&hist[d >> 8], 1);
            }
        }
        __syncthreads();
        if (t < NHI) basel[t] = atomicAdd(&gcur[t], hist[t]);  // run reservation
        curl[t] = 0;
        __syncthreads();
        #pragma unroll 4
        for (int i = 0; i < 32; i++) {
            const int e = c * PEPC + i * 256 + t;
            if (e < ET) {
                int s, d;
                if (e < E_EDGES) { s = ei[e]; d = ei[E_EDGES + e]; }
                else             { s = e - E_EDGES; d = s; }
                const int hi = d >> 8;
                const int r = atomicAdd(&curl[hi], 1);          // LDS atomic
                const int pos = basel[hi] + r;
                if (pos < CAP) ebuf[(size_t)hi * CAP + pos] = ((d & 255) << 16) | s;
            }
        }
        return;
    }
    const int idx = (blockIdx.x - NPB_PART) * 256 + t;
    if (idx < DIN * C_OUT) {
        const int k = idx >> 7, col = idx & 127;
        const int ks = k >> 5, kgrp = (k >> 3) & 3, j = k & 7;
        const int cc = col >> 4, col16 = col & 15;
        wt[((ks * 8 + cc) * 64 + kgrp * 16 + col16) * 8 + j] = f2bf(W[idx]);
    }
}

// ---------------------------------------------------------------------------
// D2: h = x@W via SWAPPED mfma (mfma(B,A)) so each lane owns ONE x-row and
//     cols {c*16 + kgrp*4 + j}: h-stores are 8B packed-bf16 (vs 2B scattered).
//     Wt staged in LDS 32 KB per K-half. Epilogue fuses att dot products.
// ---------------------------------------------------------------------------
__global__ __launch_bounds__(256) void gemm_mfma(const float* __restrict__ x,
                                                 const ushort* __restrict__ wt,
                                                 const float* __restrict__ att,
                                                 ushort* __restrict__ hb,
                                                 float* __restrict__ s_dst,
                                                 float* __restrict__ s_src) {
    __shared__ ushort lw[DIN * C_OUT / 2];   // 32 KB, one K-half fragment-ordered
    const int t = threadIdx.x;
    const int lane = t & 63, wv = t >> 6;
    const int col16 = lane & 15, kgrp = lane >> 4;
    const int rowbase = blockIdx.x * GEMM_RPB + wv * 16;
    const int hrow = rowbase + col16;        // this lane's output row
    int r0 = hrow; if (r0 >= N_NODES) r0 = N_NODES - 1;
    const float* xr0 = x + (size_t)r0 * DIN + kgrp * 8;

    f32x4 acc[8] = {};
    const short8v* lwf = (const short8v*)lw;
    #pragma unroll
    for (int ph = 0; ph < 2; ph++) {
        if (ph) __syncthreads();             // protect LDS before overwrite
        {   // stage this K-half of Wt (32 KB contiguous)
            const uint4* src = (const uint4*)(wt + ph * (DIN * C_OUT / 2));
            uint4* dst = (uint4*)lw;
            #pragma unroll
            for (int i = 0; i < 8; i++) dst[t + i * 256] = src[t + i * 256];
        }
        // hoisted fp32 A loads + in-register bf16 cvt (independent of LDS)
        short8v A0[4];
        #pragma unroll
        for (int ks = 0; ks < 4; ks++) {
            const int kg = ph * 4 + ks;
            const float4 v0 = *(const float4*)(xr0 + kg * 32);
            const float4 v1 = *(const float4*)(xr0 + kg * 32 + 4);
            short8v a;
            a[0] = f2bfs(v0.x); a[1] = f2bfs(v0.y); a[2] = f2bfs(v0.z); a[3] = f2bfs(v0.w);
            a[4] = f2bfs(v1.x); a[5] = f2bfs(v1.y); a[6] = f2bfs(v1.z); a[7] = f2bfs(v1.w);
            A0[ks] = a;
        }
        __syncthreads();
        #pragma unroll
        for (int ks = 0; ks < 4; ks++) {
            #pragma unroll
            for (int c = 0; c < 8; c++) {
                const short8v bfr = lwf[(ks * 8 + c) * 64 + lane];
                // swapped operands: D[wtcol][xrow] -> lane&15 = x row
                acc[c] = __builtin_amdgcn_mfma_f32_16x16x32_bf16(bfr, A0[ks], acc[c], 0, 0, 0);
            }
        }
    }

    // epilogue: lane holds h[hrow][c*16+kgrp*4+j], j=0..3 per acc[c]
    const bool ok = (hrow < N_NODES);
    float pd = 0.f, ps = 0.f;
    #pragma unroll
    for (int c = 0; c < 8; c++) {
        const int colb = c * 16 + kgrp * 4;
        const float4 ad = *(const float4*)(att + colb);
        const float4 as = *(const float4*)(att + C_OUT + colb);
        pd += acc[c][0] * ad.x + acc[c][1] * ad.y + acc[c][2] * ad.z + acc[c][3] * ad.w;
        ps += acc[c][0] * as.x + acc[c][1] * as.y + acc[c][2] * as.z + acc[c][3] * as.w;
        if (ok) {
            uint2 pk;
            pk.x = (uint)(ushort)f2bf(acc[c][0]) | ((uint)(ushort)f2bf(acc[c][1]) << 16);
            pk.y = (uint)(ushort)f2bf(acc[c][2]) | ((uint)(ushort)f2bf(acc[c][3]) << 16);
            *(uint2*)(hb + (size_t)hrow * C_OUT + colb) = pk;
        }
    }
    // reduce over the 4 lanes (kgrp 0..3) sharing this col16/hrow
    pd += __shfl_xor(pd, 16); pd += __shfl_xor(pd, 32);
    ps += __shfl_xor(ps, 16); ps += __shfl_xor(ps, 32);
    if (kgrp == 0 && ok) { s_dst[hrow] = pd; s_src[hrow] = ps; }
}

// ---------------------------------------------------------------------------
// D3: per-hi finalize: LDS histogram over lo, LDS scan, LDS-cursor scatter
//     -> bucket-padded esrc[] + per-node offs2 = {beg, end}.
// ---------------------------------------------------------------------------
__global__ __launch_bounds__(256) void final_kernel(const int* __restrict__ gcur,
                                                    const int* __restrict__ ebuf,
                                                    int2* __restrict__ offs2,
                                                    int* __restrict__ esrc) {
    __shared__ int histl[256], sA[256], sE[256], curl[256];
    const int t = threadIdx.x, hi = blockIdx.x;
    const int n = min(gcur[hi], CAP);
    const size_t segbase = (size_t)hi * CAP;
    histl[t] = 0;
    __syncthreads();
    for (int k = t; k < n; k += 256)
        atomicAdd(&histl[(ebuf[segbase + k] >> 16) & 255], 1);
    __syncthreads();
    const int v = histl[t];
    sA[t] = v;
    __syncthreads();
    #pragma unroll
    for (int off = 1; off < 256; off <<= 1) {   // Hillis-Steele inclusive
        const int y = (t >= off) ? sA[t - off] : 0;
        __syncthreads();
        sA[t] += y;
        __syncthreads();
    }
    sE[t] = sA[t] - v;   // exclusive
    curl[t] = 0;
    const int node = hi * 256 + t;
    if (node < N_NODES) {
        const int beg = (int)segbase + sE[t];
        offs2[node] = make_int2(beg, beg + v);
    }
    __syncthreads();
    for (int k = t; k < n; k += 256) {
        const int e2 = ebuf[segbase + k];
        const int lo = (e2 >> 16) & 255;
        const int r = atomicAdd(&curl[lo], 1);   // LDS atomic
        esrc[segbase + sE[lo] + r] = e2 & 0xFFFF;
    }
}

// ---------------------------------------------------------------------------
// D4: aggregation over per-node [beg,end) runs. 8 nodes/wave (8-lane groups;
// 2x uint4/lane = full 256 B bf16 row). Softmax without max-subtraction
// (|alpha| small, fp32-safe, ratios exact).
// ---------------------------------------------------------------------------
__global__ __launch_bounds__(256) void aggregate_kernel(
    const ushort* __restrict__ hb, const int2* __restrict__ offs2,
    const int* __restrict__ esrc, const float* __restrict__ s_dst,
    const float* __restrict__ s_src, const float* __restrict__ bias,
    float* __restrict__ out) {
    const int t = threadIdx.x;
    const int wv = t >> 6, lane = t & 63;
    const int sub = lane >> 3, l8 = lane & 7;          // 8 groups of 8 lanes
    const int node = blockIdx.x * AGG_NPB + wv * 8 + sub;
    const bool valid = (node < N_NODES);

    const int2 be = valid ? offs2[node] : make_int2(0, 0);
    const float sd = valid ? s_dst[node] : 0.f;
    float den = 0.f;
    float acc[16] = {};
    const uint4* __restrict__ h4 = (const uint4*)hb;

    for (int e = be.x; e < be.y; e++) {
        const int s = esrc[e];                         // broadcast in group
        float a = sd + s_src[s];
        a = (a > 0.f) ? a : NEG_SLOPE * a;
        const float w = __expf(a);
        den += w;
        const uint4 hv0 = h4[(size_t)s * 16 + l8];
        const uint4 hv1 = h4[(size_t)s * 16 + 8 + l8];
        acc[0]  += w * __uint_as_float(hv0.x << 16);
        acc[1]  += w * __uint_as_float(hv0.x & 0xffff0000u);
        acc[2]  += w * __uint_as_float(hv0.y << 16);
        acc[3]  += w * __uint_as_float(hv0.y & 0xffff0000u);
        acc[4]  += w * __uint_as_float(hv0.z << 16);
        acc[5]  += w * __uint_as_float(hv0.z & 0xffff0000u);
        acc[6]  += w * __uint_as_float(hv0.w << 16);
        acc[7]  += w * __uint_as_float(hv0.w & 0xffff0000u);
        acc[8]  += w * __uint_as_float(hv1.x << 16);
        acc[9]  += w * __uint_as_float(hv1.x & 0xffff0000u);
        acc[10] += w * __uint_as_float(hv1.y << 16);
        acc[11] += w * __uint_as_float(hv1.y & 0xffff0000u);
        acc[12] += w * __uint_as_float(hv1.z << 16);
        acc[13] += w * __uint_as_float(hv1.z & 0xffff0000u);
        acc[14] += w * __uint_as_float(hv1.w << 16);
        acc[15] += w * __uint_as_float(hv1.w & 0xffff0000u);
    }
    if (!valid) return;
    const float inv = 1.f / (den + 1e-16f);
    float* op = out + (size_t)node * C_OUT;
    #pragma unroll
    for (int half = 0; half < 2; half++) {
        const int base = half * 64 + l8 * 8;
        const float4 b0 = *(const float4*)(bias + base);
        const float4 b1 = *(const float4*)(bias + base + 4);
        float4 o0 = make_float4(acc[half * 8 + 0] * inv + b0.x, acc[half * 8 + 1] * inv + b0.y,
                                acc[half * 8 + 2] * inv + b0.z, acc[half * 8 + 3] * inv + b0.w);
        float4 o1 = make_float4(acc[half * 8 + 4] * inv + b1.x, acc[half * 8 + 5] * inv + b1.y,
                                acc[half * 8 + 6] * inv + b1.z, acc[half * 8 + 7] * inv + b1.w);
        *(float4*)(op + base)     = o0;
        *(float4*)(op + base + 4) = o1;
    }
}

// ---------------------------------------------------------------------------
extern "C" void kernel_launch(void* const* d_in, const int* in_sizes, int n_in,
                              void* d_out, int out_size, void* d_ws, size_t ws_size,
                              hipStream_t stream) {
    const float* x    = (const float*)d_in[0];
    const int*   ei   = (const int*)d_in[1];
    const float* W    = (const float*)d_in[2];
    const float* att  = (const float*)d_in[3];
    const float* bias = (const float*)d_in[4];
    float* out = (float*)d_out;

    // workspace layout (~23 MB); all segments 16 B-aligned
    ushort* wt    = (ushort*)d_ws;                           // 32768 (64 KB)
    ushort* hbuf  = wt + DIN * C_OUT;                        // N*128 bf16 (12.8 MB)
    int*    ebuf  = (int*)(hbuf + (size_t)N_NODES * C_OUT);  // NHI*CAP int (4.8 MB)
    int*    esrc  = ebuf + (size_t)NHI * CAP;                // NHI*CAP int (4.8 MB)
    float*  s_src = (float*)(esrc + (size_t)NHI * CAP);      // N
    float*  s_dst = s_src + N_NODES;                         // N
    int2*   offs2 = (int2*)(s_dst + N_NODES);                // N int2 (400 KB)
    int*    gcur  = (int*)(offs2 + N_NODES);                 // NHI

    hipMemsetAsync(gcur, 0, NHI * sizeof(int), stream);
    part_wconv<<<NPB_PART + WCONV_BLOCKS, 256, 0, stream>>>(W, ei, wt, gcur, ebuf);
    gemm_mfma<<<GEMM_BLOCKS, 256, 0, stream>>>(x, wt, att, hbuf, s_dst, s_src);
    final_kernel<<<NHI, 256, 0, stream>>>(gcur, ebuf, offs2, esrc);
    aggregate_kernel<<<AGG_BLOCKS, 256, 0, stream>>>(
        hbuf, offs2, esrc, s_dst, s_src, bias, out);
}

// Round 13
// 90.681 us; speedup vs baseline: 1.1178x; 1.1178x over previous
//
#include <hip/hip_runtime.h>
#include <hip/hip_bf16.h>

constexpr int N_NODES = 50000;
constexpr int DIN     = 256;
constexpr int C_OUT   = 128;
constexpr int E_EDGES = 800000;
constexpr int ET      = E_EDGES + N_NODES;   // with self-loops
constexpr float NEG_SLOPE = 0.2f;

constexpr int NHI      = 196;                 // hi = dst >> 8
constexpr int CAP      = 6144;                // bucket capacity (mean 4337)
constexpr int PEPC     = 8192;                // edges per part block (256 thr x 32)
constexpr int NPB_PART = (ET + PEPC - 1) / PEPC;                   // 104
constexpr int GEMM_RPB    = 64;
constexpr int GEMM_BLOCKS = (N_NODES + GEMM_RPB - 1) / GEMM_RPB;   // 782
constexpr int AGG_NPB     = 32;
constexpr int AGG_BLOCKS  = (N_NODES + AGG_NPB - 1) / AGG_NPB;     // 1563

typedef __attribute__((ext_vector_type(8))) short short8v;
typedef __attribute__((ext_vector_type(4))) float f32x4;

static __device__ __forceinline__ ushort f2bf(float f) {
    __hip_bfloat16 b = __float2bfloat16(f);
    return *reinterpret_cast<ushort*>(&b);
}
static __device__ __forceinline__ short f2bfs(float f) {
    __hip_bfloat16 b = __float2bfloat16(f);
    return *reinterpret_cast<short*>(&b);
}

// ---------------------------------------------------------------------------
// D1: Wt -> bf16 fragment-ordered + zero gcur (block 0). No memset dispatch.
// fragpos(ks,c,kgrp,col16,j) = ((ks*8+c)*64 + kgrp*16 + col16)*8 + j
// ---------------------------------------------------------------------------
__global__ __launch_bounds__(256) void wconv_kernel(const float* __restrict__ W,
                                                    ushort* __restrict__ wt,
                                                    int* __restrict__ gcur) {
    const int t = threadIdx.x;
    const int idx = blockIdx.x * 256 + t;
    if (idx < DIN * C_OUT) {
        const int k = idx >> 7, col = idx & 127;
        const int ks = k >> 5, kgrp = (k >> 3) & 3, j = k & 7;
        const int cc = col >> 4, col16 = col & 15;
        wt[((ks * 8 + cc) * 64 + kgrp * 16 + col16) * 8 + j] = f2bf(W[idx]);
    }
    if (blockIdx.x == 0 && t < NHI) gcur[t] = 0;
}

// ---------------------------------------------------------------------------
// D2 (fused): blocks [0,NPB_PART): bucket-partition edges -> packed ebuf
//   entry (lo<<16)|src (LDS histogram + one returning global atomic per
//   (block,bucket) + LDS-cursor scatter).
//   blocks [NPB_PART,+GEMM_BLOCKS): h = x@W via SWAPPED mfma(B,A): each lane
//   owns ONE x-row -> h-stores are packed 8 B bf16 pairs (not 2 B scattered).
//   Wt staged in LDS 32 KB per K-half; att dots fused in epilogue.
// ---------------------------------------------------------------------------
__global__ __launch_bounds__(256) void part_gemm(const float* __restrict__ x,
                                                 const ushort* __restrict__ wt,
                                                 const float* __restrict__ att,
                                                 const int* __restrict__ ei,
                                                 ushort* __restrict__ hb,
                                                 float* __restrict__ s_dst,
                                                 float* __restrict__ s_src,
                                                 int* __restrict__ gcur,
                                                 int* __restrict__ ebuf) {
    __shared__ ushort lw[DIN * C_OUT / 2];   // 32 KB (gemm); part aliases 3 KB
    const int t = threadIdx.x;

    if (blockIdx.x < NPB_PART) {             // ---- partition path ----
        int* li    = (int*)lw;
        int* hist  = li;                      // [256]
        int* basel = li + 256;                // [256]
        int* curl  = li + 512;                // [256]
        const int c = blockIdx.x;
        hist[t] = 0;
        __syncthreads();
        #pragma unroll 4
        for (int i = 0; i < 32; i++) {
            const int e = c * PEPC + i * 256 + t;
            if (e < ET) {
                const int d = (e < E_EDGES) ? ei[E_EDGES + e] : (e - E_EDGES);
                atomicAdd(&hist[d >> 8], 1);
            }
        }
        __syncthreads();
        if (t < NHI) basel[t] = atomicAdd(&gcur[t], hist[t]);  // run reservation
        curl[t] = 0;
        __syncthreads();
        #pragma unroll 4
        for (int i = 0; i < 32; i++) {
            const int e = c * PEPC + i * 256 + t;
            if (e < ET) {
                int s, d;
                if (e < E_EDGES) { s = ei[e]; d = ei[E_EDGES + e]; }
                else             { s = e - E_EDGES; d = s; }
                const int hi = d >> 8;
                const int r = atomicAdd(&curl[hi], 1);          // LDS atomic
                const int pos = basel[hi] + r;
                if (pos < CAP) ebuf[(size_t)hi * CAP + pos] = ((d & 255) << 16) | s;
            }
        }
        return;
    }

    // ---- GEMM path (swapped-operand MFMA) ----
    const int gb = blockIdx.x - NPB_PART;
    const int lane = t & 63, wv = t >> 6;
    const int col16 = lane & 15, kgrp = lane >> 4;
    const int rowbase = gb * GEMM_RPB + wv * 16;
    const int hrow = rowbase + col16;        // this lane's output row
    int r0 = hrow; if (r0 >= N_NODES) r0 = N_NODES - 1;
    const float* xr0 = x + (size_t)r0 * DIN + kgrp * 8;

    f32x4 acc[8] = {};
    const short8v* lwf = (const short8v*)lw;
    #pragma unroll
    for (int ph = 0; ph < 2; ph++) {
        if (ph) __syncthreads();             // protect LDS before overwrite
        {   // stage this K-half of Wt (32 KB contiguous)
            const uint4* src = (const uint4*)(wt + ph * (DIN * C_OUT / 2));
            uint4* dst = (uint4*)lw;
            #pragma unroll
            for (int i = 0; i < 8; i++) dst[t + i * 256] = src[t + i * 256];
        }
        // hoisted fp32 A loads + in-register bf16 cvt (independent of LDS)
        short8v A0[4];
        #pragma unroll
        for (int ks = 0; ks < 4; ks++) {
            const int kg = ph * 4 + ks;
            const float4 v0 = *(const float4*)(xr0 + kg * 32);
            const float4 v1 = *(const float4*)(xr0 + kg * 32 + 4);
            short8v a;
            a[0] = f2bfs(v0.x); a[1] = f2bfs(v0.y); a[2] = f2bfs(v0.z); a[3] = f2bfs(v0.w);
            a[4] = f2bfs(v1.x); a[5] = f2bfs(v1.y); a[6] = f2bfs(v1.z); a[7] = f2bfs(v1.w);
            A0[ks] = a;
        }
        __syncthreads();
        #pragma unroll
        for (int ks = 0; ks < 4; ks++) {
            #pragma unroll
            for (int c = 0; c < 8; c++) {
                const short8v bfr = lwf[(ks * 8 + c) * 64 + lane];
                // swapped operands: D[wtcol][xrow] -> lane&15 = x row
                acc[c] = __builtin_amdgcn_mfma_f32_16x16x32_bf16(bfr, A0[ks], acc[c], 0, 0, 0);
            }
        }
    }

    // epilogue: lane holds h[hrow][c*16+kgrp*4+j], j=0..3 per acc[c]
    const bool ok = (hrow < N_NODES);
    float pd = 0.f, ps = 0.f;
    #pragma unroll
    for (int c = 0; c < 8; c++) {
        const int colb = c * 16 + kgrp * 4;
        const float4 ad = *(const float4*)(att + colb);
        const float4 as = *(const float4*)(att + C_OUT + colb);
        pd += acc[c][0] * ad.x + acc[c][1] * ad.y + acc[c][2] * ad.z + acc[c][3] * ad.w;
        ps += acc[c][0] * as.x + acc[c][1] * as.y + acc[c][2] * as.z + acc[c][3] * as.w;
        if (ok) {
            uint2 pk;
            pk.x = (uint)(ushort)f2bf(acc[c][0]) | ((uint)(ushort)f2bf(acc[c][1]) << 16);
            pk.y = (uint)(ushort)f2bf(acc[c][2]) | ((uint)(ushort)f2bf(acc[c][3]) << 16);
            *(uint2*)(hb + (size_t)hrow * C_OUT + colb) = pk;
        }
    }
    // reduce over the 4 lanes (kgrp 0..3) sharing this col16/hrow
    pd += __shfl_xor(pd, 16); pd += __shfl_xor(pd, 32);
    ps += __shfl_xor(ps, 16); ps += __shfl_xor(ps, 32);
    if (kgrp == 0 && ok) { s_dst[hrow] = pd; s_src[hrow] = ps; }
}

// ---------------------------------------------------------------------------
// D3: per-hi finalize: LDS histogram over lo, LDS scan, LDS-cursor scatter
//     -> bucket-padded esrc[] + per-node offs2 = {beg, end}.
// ---------------------------------------------------------------------------
__global__ __launch_bounds__(256) void final_kernel(const int* __restrict__ gcur,
                                                    const int* __restrict__ ebuf,
                                                    int2* __restrict__ offs2,
                                                    int* __restrict__ esrc) {
    __shared__ int histl[256], sA[256], sE[256], curl[256];
    const int t = threadIdx.x, hi = blockIdx.x;
    const int n = min(gcur[hi], CAP);
    const size_t segbase = (size_t)hi * CAP;
    histl[t] = 0;
    __syncthreads();
    for (int k = t; k < n; k += 256)
        atomicAdd(&histl[(ebuf[segbase + k] >> 16) & 255], 1);
    __syncthreads();
    const int v = histl[t];
    sA[t] = v;
    __syncthreads();
    #pragma unroll
    for (int off = 1; off < 256; off <<= 1) {   // Hillis-Steele inclusive
        const int y = (t >= off) ? sA[t - off] : 0;
        __syncthreads();
        sA[t] += y;
        __syncthreads();
    }
    sE[t] = sA[t] - v;   // exclusive
    curl[t] = 0;
    const int node = hi * 256 + t;
    if (node < N_NODES) {
        const int beg = (int)segbase + sE[t];
        offs2[node] = make_int2(beg, beg + v);
    }
    __syncthreads();
    for (int k = t; k < n; k += 256) {
        const int e2 = ebuf[segbase + k];
        const int lo = (e2 >> 16) & 255;
        const int r = atomicAdd(&curl[lo], 1);   // LDS atomic
        esrc[segbase + sE[lo] + r] = e2 & 0xFFFF;
    }
}

// ---------------------------------------------------------------------------
// D4: aggregation over per-node [beg,end) runs. 8 nodes/wave (8-lane groups;
// 2x uint4/lane = full 256 B bf16 row). Softmax without max-subtraction
// (|alpha| small, fp32-safe, ratios exact).
// ---------------------------------------------------------------------------
__global__ __launch_bounds__(256) void aggregate_kernel(
    const ushort* __restrict__ hb, const int2* __restrict__ offs2,
    const int* __restrict__ esrc, const float* __restrict__ s_dst,
    const float* __restrict__ s_src, const float* __restrict__ bias,
    float* __restrict__ out) {
    const int t = threadIdx.x;
    const int wv = t >> 6, lane = t & 63;
    const int sub = lane >> 3, l8 = lane & 7;          // 8 groups of 8 lanes
    const int node = blockIdx.x * AGG_NPB + wv * 8 + sub;
    const bool valid = (node < N_NODES);

    const int2 be = valid ? offs2[node] : make_int2(0, 0);
    const float sd = valid ? s_dst[node] : 0.f;
    float den = 0.f;
    float acc[16] = {};
    const uint4* __restrict__ h4 = (const uint4*)hb;

    for (int e = be.x; e < be.y; e++) {
        const int s = esrc[e];                         // broadcast in group
        float a = sd + s_src[s];
        a = (a > 0.f) ? a : NEG_SLOPE * a;
        const float w = __expf(a);
        den += w;
        const uint4 hv0 = h4[(size_t)s * 16 + l8];
        const uint4 hv1 = h4[(size_t)s * 16 + 8 + l8];
        acc[0]  += w * __uint_as_float(hv0.x << 16);
        acc[1]  += w * __uint_as_float(hv0.x & 0xffff0000u);
        acc[2]  += w * __uint_as_float(hv0.y << 16);
        acc[3]  += w * __uint_as_float(hv0.y & 0xffff0000u);
        acc[4]  += w * __uint_as_float(hv0.z << 16);
        acc[5]  += w * __uint_as_float(hv0.z & 0xffff0000u);
        acc[6]  += w * __uint_as_float(hv0.w << 16);
        acc[7]  += w * __uint_as_float(hv0.w & 0xffff0000u);
        acc[8]  += w * __uint_as_float(hv1.x << 16);
        acc[9]  += w * __uint_as_float(hv1.x & 0xffff0000u);
        acc[10] += w * __uint_as_float(hv1.y << 16);
        acc[11] += w * __uint_as_float(hv1.y & 0xffff0000u);
        acc[12] += w * __uint_as_float(hv1.z << 16);
        acc[13] += w * __uint_as_float(hv1.z & 0xffff0000u);
        acc[14] += w * __uint_as_float(hv1.w << 16);
        acc[15] += w * __uint_as_float(hv1.w & 0xffff0000u);
    }
    if (!valid) return;
    const float inv = 1.f / (den + 1e-16f);
    float* op = out + (size_t)node * C_OUT;
    #pragma unroll
    for (int half = 0; half < 2; half++) {
        const int base = half * 64 + l8 * 8;
        const float4 b0 = *(const float4*)(bias + base);
        const float4 b1 = *(const float4*)(bias + base + 4);
        float4 o0 = make_float4(acc[half * 8 + 0] * inv + b0.x, acc[half * 8 + 1] * inv + b0.y,
                                acc[half * 8 + 2] * inv + b0.z, acc[half * 8 + 3] * inv + b0.w);
        float4 o1 = make_float4(acc[half * 8 + 4] * inv + b1.x, acc[half * 8 + 5] * inv + b1.y,
                                acc[half * 8 + 6] * inv + b1.z, acc[half * 8 + 7] * inv + b1.w);
        *(float4*)(op + base)     = o0;
        *(float4*)(op + base + 4) = o1;
    }
}

// ---------------------------------------------------------------------------
extern "C" void kernel_launch(void* const* d_in, const int* in_sizes, int n_in,
                              void* d_out, int out_size, void* d_ws, size_t ws_size,
                              hipStream_t stream) {
    const float* x    = (const float*)d_in[0];
    const int*   ei   = (const int*)d_in[1];
    const float* W    = (const float*)d_in[2];
    const float* att  = (const float*)d_in[3];
    const float* bias = (const float*)d_in[4];
    float* out = (float*)d_out;

    // workspace layout (~23 MB); all segments 16 B-aligned
    ushort* wt    = (ushort*)d_ws;                           // 32768 (64 KB)
    ushort* hbuf  = wt + DIN * C_OUT;                        // N*128 bf16 (12.8 MB)
    int*    ebuf  = (int*)(hbuf + (size_t)N_NODES * C_OUT);  // NHI*CAP int (4.8 MB)
    int*    esrc  = ebuf + (size_t)NHI * CAP;                // NHI*CAP int (4.8 MB)
    float*  s_src = (float*)(esrc + (size_t)NHI * CAP);      // N
    float*  s_dst = s_src + N_NODES;                         // N
    int2*   offs2 = (int2*)(s_dst + N_NODES);                // N int2 (400 KB)
    int*    gcur  = (int*)(offs2 + N_NODES);                 // NHI

    wconv_kernel<<<(DIN * C_OUT + 255) / 256, 256, 0, stream>>>(W, wt, gcur);
    part_gemm<<<NPB_PART + GEMM_BLOCKS, 256, 0, stream>>>(
        x, wt, att, ei, hbuf, s_dst, s_src, gcur, ebuf);
    final_kernel<<<NHI, 256, 0, stream>>>(gcur, ebuf, offs2, esrc);
    aggregate_kernel<<<AGG_BLOCKS, 256, 0, stream>>>(
        hbuf, offs2, esrc, s_dst, s_src, bias, out);
}